// Round 2
// baseline (854.126 us; speedup 1.0000x reference)
//
#include <hip/hip_runtime.h>
#include <hip/hip_bf16.h>

// ---------------- degree / dinv ----------------
__global__ void k_init_deg(float* __restrict__ deg, int n) {
    int i = blockIdx.x * blockDim.x + threadIdx.x;
    if (i < n) deg[i] = 1.0f;  // self-loop contributes 1 to deg
}

__global__ void k_deg(const int* __restrict__ dst, int E, float* __restrict__ deg) {
    int i = blockIdx.x * blockDim.x + threadIdx.x;
    if (i < E) atomicAdd(&deg[dst[i]], 1.0f);
}

__global__ void k_dinv(const float* __restrict__ deg, float* __restrict__ dinv, int n) {
    int i = blockIdx.x * blockDim.x + threadIdx.x;
    if (i < n) dinv[i] = rsqrtf(deg[i]);  // deg >= 1 always
}

// ---------------- layer 1 GEMM: h1s = (x @ W1) * dinv ----------------
// x: [N,128] f32, W1: [128,64] f32, h1s: [N,64] f32. 4 nodes per 256-thread block.
__global__ __launch_bounds__(256) void k_gemm1(const float* __restrict__ x,
                                               const float* __restrict__ W1,
                                               const float* __restrict__ dinv,
                                               float* __restrict__ h1s, int n) {
    __shared__ float W1s[128 * 64];  // 32 KB
    __shared__ float xs[4][128];     // 2 KB
    int t = threadIdx.x;
    for (int i = t; i < 128 * 64; i += 256) W1s[i] = W1[i];
    int node0 = blockIdx.x * 4;
    for (int i = t; i < 4 * 128; i += 256) {
        int nl = i >> 7, k = i & 127;
        int node = node0 + nl;
        xs[nl][k] = (node < n) ? x[(size_t)node * 128 + k] : 0.0f;
    }
    __syncthreads();
    int nl = t >> 6, c = t & 63;  // one wave per node, lane = output col
    int node = node0 + nl;
    if (node < n) {
        float acc = 0.0f;
#pragma unroll 8
        for (int k = 0; k < 128; k++) acc = fmaf(xs[nl][k], W1s[k * 64 + c], acc);
        h1s[(size_t)node * 64 + c] = acc * dinv[node];
    }
}

// ---------------- edge scatter, width 64: acc[dst] += h[src] ----------------
__global__ __launch_bounds__(256) void k_scatter64(const int* __restrict__ src,
                                                   const int* __restrict__ dst, int E,
                                                   const float* __restrict__ h,
                                                   float* __restrict__ acc) {
    int idx = blockIdx.x * blockDim.x + threadIdx.x;  // E*64 = 102.4M < 2^31
    if (idx < E * 64) {
        int e = idx >> 6, c = idx & 63;  // one wave = one edge (coalesced 256B)
        int s = src[e], d = dst[e];
        atomicAdd(&acc[(size_t)d * 64 + c], h[(size_t)s * 64 + c]);
    }
}

// ---------------- edge scatter, width 32 ----------------
__global__ __launch_bounds__(256) void k_scatter32(const int* __restrict__ src,
                                                   const int* __restrict__ dst, int E,
                                                   const float* __restrict__ h,
                                                   float* __restrict__ acc) {
    int idx = blockIdx.x * blockDim.x + threadIdx.x;  // E*32 = 51.2M
    if (idx < E * 32) {
        int e = idx >> 5, c = idx & 31;
        int s = src[e], d = dst[e];
        atomicAdd(&acc[(size_t)d * 32 + c], h[(size_t)s * 32 + c]);
    }
}

// ---------------- finalize L1 + GEMM2: h2s = (relu((acc1+h1s)*dinv + b1) @ W2) * dinv ----
__global__ __launch_bounds__(256) void k_fin1_gemm2(const float* __restrict__ acc1,
                                                    const float* __restrict__ h1s,
                                                    const float* __restrict__ dinv,
                                                    const float* __restrict__ b1,
                                                    const float* __restrict__ W2,
                                                    float* __restrict__ h2s, int n) {
    __shared__ float W2s[64 * 32];  // 8 KB
    __shared__ float hb[4][64];
    int t = threadIdx.x;
    for (int i = t; i < 64 * 32; i += 256) W2s[i] = W2[i];
    int node0 = blockIdx.x * 4;
    int nl = t >> 6, c = t & 63;
    int node = node0 + nl;
    float hval = 0.0f;
    float di = (node < n) ? dinv[node] : 0.0f;
    if (node < n) {
        // self-loop contribution = h1s[node] (src==dst), then post-scale + bias + relu
        float v = (acc1[(size_t)node * 64 + c] + h1s[(size_t)node * 64 + c]) * di + b1[c];
        hval = fmaxf(v, 0.0f);
    }
    hb[nl][c] = hval;
    __syncthreads();
    if (node < n && c < 32) {
        float s = 0.0f;
#pragma unroll 8
        for (int k = 0; k < 64; k++) s = fmaf(hb[nl][k], W2s[k * 32 + c], s);
        h2s[(size_t)node * 32 + c] = s * di;
    }
}

// ---------------- finalize L2 -> f32 out ----------------
__global__ __launch_bounds__(256) void k_fin2(const float* __restrict__ acc2,
                                              const float* __restrict__ h2s,
                                              const float* __restrict__ dinv,
                                              const float* __restrict__ b2v,
                                              float* __restrict__ out, int n) {
    int idx = blockIdx.x * blockDim.x + threadIdx.x;  // n*32 = 3.2M
    if (idx < n * 32) {
        int node = idx >> 5, c = idx & 31;
        out[idx] = (acc2[idx] + h2s[idx]) * dinv[node] + b2v[c];
    }
}

extern "C" void kernel_launch(void* const* d_in, const int* in_sizes, int n_in,
                              void* d_out, int out_size, void* d_ws, size_t ws_size,
                              hipStream_t stream) {
    const float* x  = (const float*)d_in[0];
    const int*   ei = (const int*)d_in[1];
    const float* W1 = (const float*)d_in[2];
    const float* b1 = (const float*)d_in[3];
    const float* W2 = (const float*)d_in[4];
    const float* b2 = (const float*)d_in[5];
    float* out = (float*)d_out;

    const int N = in_sizes[0] / 128;  // 100000
    const int E = in_sizes[1] / 2;    // 1600000
    const int* src = ei;
    const int* dst = ei + E;

    float* ws   = (float*)d_ws;
    float* deg  = ws;                        // N
    float* dinv = deg + N;                   // N
    float* h1s  = dinv + N;                  // N*64
    float* acc1 = h1s + (size_t)N * 64;      // N*64
    float* h2s  = acc1 + (size_t)N * 64;     // N*32
    float* acc2 = h2s + (size_t)N * 32;      // N*32  -> total 194*N floats ~ 77.6 MB

    hipMemsetAsync(acc1, 0, (size_t)N * 64 * sizeof(float), stream);
    hipMemsetAsync(acc2, 0, (size_t)N * 32 * sizeof(float), stream);

    k_init_deg<<<(N + 255) / 256, 256, 0, stream>>>(deg, N);
    k_deg<<<(E + 255) / 256, 256, 0, stream>>>(dst, E, deg);
    k_dinv<<<(N + 255) / 256, 256, 0, stream>>>(deg, dinv, N);

    k_gemm1<<<(N + 3) / 4, 256, 0, stream>>>(x, W1, dinv, h1s, N);

    int t1 = E * 64;  // 102.4M
    k_scatter64<<<(t1 + 255) / 256, 256, 0, stream>>>(src, dst, E, h1s, acc1);

    k_fin1_gemm2<<<(N + 3) / 4, 256, 0, stream>>>(acc1, h1s, dinv, b1, W2, h2s, N);

    int t2 = E * 32;  // 51.2M
    k_scatter32<<<(t2 + 255) / 256, 256, 0, stream>>>(src, dst, E, h2s, acc2);

    k_fin2<<<(N * 32 + 255) / 256, 256, 0, stream>>>(acc2, h2s, dinv, b2, out, N);
}

// Round 4
// 505.105 us; speedup vs baseline: 1.6910x; 1.6910x over previous
//
#include <hip/hip_runtime.h>
#include <hip/hip_bf16.h>

// ---------------- CSR build ----------------
__global__ void k_count(const int* __restrict__ dst, int E, int* __restrict__ cnt) {
    int i = blockIdx.x * blockDim.x + threadIdx.x;
    if (i < E) atomicAdd(&cnt[dst[i]], 1);
}

// per-256-block exclusive scan + block sums
__global__ __launch_bounds__(256) void k_scanA(const int* __restrict__ cnt,
                                               int* __restrict__ rowpart,
                                               int* __restrict__ blocksum, int n) {
    __shared__ int sh[256];
    int t = threadIdx.x, i = blockIdx.x * 256 + t;
    int v = (i < n) ? cnt[i] : 0;
    sh[t] = v; __syncthreads();
    for (int off = 1; off < 256; off <<= 1) {
        int tmp = (t >= off) ? sh[t - off] : 0; __syncthreads();
        sh[t] += tmp; __syncthreads();
    }
    if (i < n) rowpart[i] = sh[t] - v;          // exclusive within block
    if (t == 255) blocksum[blockIdx.x] = sh[255];
}

// scan the (<=1024) block sums in one block
__global__ __launch_bounds__(1024) void k_scanB(const int* __restrict__ blocksum,
                                                int* __restrict__ blockoff, int nb) {
    __shared__ int sh[1024];
    int t = threadIdx.x;
    int v = (t < nb) ? blocksum[t] : 0;
    sh[t] = v; __syncthreads();
    for (int off = 1; off < 1024; off <<= 1) {
        int tmp = (t >= off) ? sh[t - off] : 0; __syncthreads();
        sh[t] += tmp; __syncthreads();
    }
    if (t < nb) blockoff[t] = sh[t] - v;        // exclusive
}

// rowstart = rowpart + blockoff; dinv = rsqrt(cnt+1)  (self-loop adds 1 to degree)
__global__ void k_scanC(const int* __restrict__ rowpart, const int* __restrict__ blockoff,
                        const int* __restrict__ cnt, int* __restrict__ rowstart,
                        float* __restrict__ dinv, int n) {
    int i = blockIdx.x * blockDim.x + threadIdx.x;
    if (i < n) {
        rowstart[i] = rowpart[i] + blockoff[i >> 8];
        dinv[i] = rsqrtf((float)(cnt[i] + 1));
    }
}

__global__ void k_fill(const int* __restrict__ src, const int* __restrict__ dst, int E,
                       const int* __restrict__ rowstart, int* __restrict__ cursor,
                       int* __restrict__ srclist) {
    int e = blockIdx.x * blockDim.x + threadIdx.x;
    if (e < E) {
        int d = dst[e];
        int p = atomicAdd(&cursor[d], 1);
        srclist[rowstart[d] + p] = src[e];
    }
}

// ---------------- layer 1 GEMM: h1s = (x @ W1) * dinv ----------------
__global__ __launch_bounds__(256) void k_gemm1(const float* __restrict__ x,
                                               const float* __restrict__ W1,
                                               const float* __restrict__ dinv,
                                               float* __restrict__ h1s, int n) {
    __shared__ float W1s[128 * 64];  // 32 KB
    __shared__ float xs[4][128];
    int t = threadIdx.x;
    for (int i = t; i < 128 * 64; i += 256) W1s[i] = W1[i];
    int node0 = blockIdx.x * 4;
    for (int i = t; i < 4 * 128; i += 256) {
        int nl = i >> 7, k = i & 127;
        int node = node0 + nl;
        xs[nl][k] = (node < n) ? x[(size_t)node * 128 + k] : 0.0f;
    }
    __syncthreads();
    int nl = t >> 6, c = t & 63;
    int node = node0 + nl;
    if (node < n) {
        float acc = 0.0f;
#pragma unroll 8
        for (int k = 0; k < 128; k++) acc = fmaf(xs[nl][k], W1s[k * 64 + c], acc);
        h1s[(size_t)node * 64 + c] = acc * dinv[node];
    }
}

// ------- L1 gather + finalize + GEMM2: h2s = (relu((gather+self)*dinv + b1) @ W2) * dinv ----
// one wave per node, 4 nodes per block
__global__ __launch_bounds__(256) void k_gather_l1(const int* __restrict__ rowstart,
                                                   const int* __restrict__ cnt,
                                                   const int* __restrict__ srclist,
                                                   const float* __restrict__ h1s,
                                                   const float* __restrict__ dinv,
                                                   const float* __restrict__ b1,
                                                   const float* __restrict__ W2,
                                                   float* __restrict__ h2s, int n) {
    __shared__ float W2s[64 * 32];  // 8 KB
    __shared__ float hb[4][64];
    int t = threadIdx.x;
    for (int i = t; i < 64 * 32; i += 256) W2s[i] = W2[i];
    int wid = t >> 6, lane = t & 63;
    int node = blockIdx.x * 4 + wid;
    bool valid = (node < n);

    int row = valid ? rowstart[node] : 0;
    int m_all = valid ? cnt[node] : 0;
    float acc = 0.0f;
    for (int j0 = 0; j0 < m_all; j0 += 64) {
        int m = min(64, m_all - j0);  // wave-uniform
        int sidx = (lane < m) ? srclist[row + j0 + lane] : 0;
        int j = 0;
        for (; j + 4 <= m; j += 4) {  // uniform bounds, uniform shfl lanes
            int s0 = __shfl(sidx, j), s1 = __shfl(sidx, j + 1);
            int s2 = __shfl(sidx, j + 2), s3 = __shfl(sidx, j + 3);
            float a0 = h1s[(size_t)s0 * 64 + lane];
            float a1 = h1s[(size_t)s1 * 64 + lane];
            float a2 = h1s[(size_t)s2 * 64 + lane];
            float a3 = h1s[(size_t)s3 * 64 + lane];
            acc += (a0 + a1) + (a2 + a3);
        }
        for (; j < m; j++) {
            int s = __shfl(sidx, j);
            acc += h1s[(size_t)s * 64 + lane];
        }
    }
    float di = valid ? dinv[node] : 0.0f;
    if (valid) {
        float v = (acc + h1s[(size_t)node * 64 + lane]) * di + b1[lane];  // self-loop folded
        hb[wid][lane] = fmaxf(v, 0.0f);
    }
    __syncthreads();  // covers both W2s staging and hb writes
    if (valid && lane < 32) {
        float s = 0.0f;
#pragma unroll 8
        for (int k = 0; k < 64; k++) s = fmaf(hb[wid][k], W2s[k * 32 + lane], s);
        h2s[(size_t)node * 32 + lane] = s * di;
    }
}

// ------- L2 gather + finalize: out = (gather+self)*dinv + b2 ----
// one wave per node; half-wave pairs process 2 edges per step (rows are 128B)
__global__ __launch_bounds__(256) void k_gather_l2(const int* __restrict__ rowstart,
                                                   const int* __restrict__ cnt,
                                                   const int* __restrict__ srclist,
                                                   const float* __restrict__ h2s,
                                                   const float* __restrict__ dinv,
                                                   const float* __restrict__ b2v,
                                                   float* __restrict__ out, int n) {
    int t = threadIdx.x;
    int wid = t >> 6, lane = t & 63;
    int node = blockIdx.x * 4 + wid;
    if (node >= n) return;  // whole wave exits together; no barriers below
    int c = lane & 31, half = lane >> 5;

    int row = rowstart[node], m_all = cnt[node];
    float acc = 0.0f;
    for (int j0 = 0; j0 < m_all; j0 += 64) {
        int m = min(64, m_all - j0);  // wave-uniform, >= 1
        int sidx = (lane < m) ? srclist[row + j0 + lane] : 0;
        int jj = 0;
        for (; jj + 8 <= m; jj += 8) {  // uniform trip count; all lanes shfl
            int s0 = __shfl(sidx, jj + half),     s1 = __shfl(sidx, jj + 2 + half);
            int s2 = __shfl(sidx, jj + 4 + half), s3 = __shfl(sidx, jj + 6 + half);
            float a0 = h2s[(size_t)s0 * 32 + c];
            float a1 = h2s[(size_t)s1 * 32 + c];
            float a2 = h2s[(size_t)s2 * 32 + c];
            float a3 = h2s[(size_t)s3 * 32 + c];
            acc += (a0 + a1) + (a2 + a3);
        }
        for (; jj < m; jj += 2) {
            int jidx = jj + half;
            int s = __shfl(sidx, min(jidx, m - 1));  // uniform shfl; clamp lane
            if (jidx < m) acc += h2s[(size_t)s * 32 + c];  // predicate the use only
        }
    }
    acc += __shfl_xor(acc, 32);  // combine the two halves (all lanes active)
    if (half == 0) {
        float di = dinv[node];
        out[(size_t)node * 32 + c] = (acc + h2s[(size_t)node * 32 + c]) * di + b2v[c];
    }
}

extern "C" void kernel_launch(void* const* d_in, const int* in_sizes, int n_in,
                              void* d_out, int out_size, void* d_ws, size_t ws_size,
                              hipStream_t stream) {
    const float* x  = (const float*)d_in[0];
    const int*   ei = (const int*)d_in[1];
    const float* W1 = (const float*)d_in[2];
    const float* b1 = (const float*)d_in[3];
    const float* W2 = (const float*)d_in[4];
    const float* b2 = (const float*)d_in[5];
    float* out = (float*)d_out;

    const int N = in_sizes[0] / 128;  // 100000
    const int E = in_sizes[1] / 2;    // 1600000
    const int* src = ei;
    const int* dst = ei + E;

    char* p = (char*)d_ws;
    int* cnt      = (int*)p;            p += (size_t)N * 4;
    int* cursor   = (int*)p;            p += (size_t)N * 4;
    int* rowpart  = (int*)p;            p += (size_t)N * 4;
    int* rowstart = (int*)p;            p += (size_t)N * 4;
    int* blocksum = (int*)p;            p += 1024 * 4;
    int* blockoff = (int*)p;            p += 1024 * 4;
    int* srclist  = (int*)p;            p += (size_t)E * 4;
    float* dinv   = (float*)p;          p += (size_t)N * 4;
    float* h1s    = (float*)p;          p += (size_t)N * 64 * 4;
    float* h2s    = (float*)p;          p += (size_t)N * 32 * 4;
    // total ~47 MB

    const int NB = (N + 255) / 256;  // 391 <= 1024

    hipMemsetAsync(cnt, 0, (size_t)N * 4, stream);
    hipMemsetAsync(cursor, 0, (size_t)N * 4, stream);

    k_count<<<(E + 255) / 256, 256, 0, stream>>>(dst, E, cnt);
    k_scanA<<<NB, 256, 0, stream>>>(cnt, rowpart, blocksum, N);
    k_scanB<<<1, 1024, 0, stream>>>(blocksum, blockoff, NB);
    k_scanC<<<NB, 256, 0, stream>>>(rowpart, blockoff, cnt, rowstart, dinv, N);
    k_fill<<<(E + 255) / 256, 256, 0, stream>>>(src, dst, E, rowstart, cursor, srclist);

    k_gemm1<<<(N + 3) / 4, 256, 0, stream>>>(x, W1, dinv, h1s, N);
    k_gather_l1<<<(N + 3) / 4, 256, 0, stream>>>(rowstart, cnt, srclist, h1s, dinv, b1, W2, h2s, N);
    k_gather_l2<<<(N + 3) / 4, 256, 0, stream>>>(rowstart, cnt, srclist, h2s, dinv, b2, out, N);
}

// Round 7
// 406.273 us; speedup vs baseline: 2.1023x; 1.2433x over previous
//
#include <hip/hip_runtime.h>
#include <hip/hip_bf16.h>

// Buckets are 256 consecutive nodes: bucket(d) = d >> 8. Since CSR rows are in
// node order, bucket b's CSR region is [bucket_base[b], bucket_base[b+1]).

#define MAXBUCK 512  // supports N <= 131072

// ---------------- zero the bucket totals (replaces hipMemsetAsync) ----------------
__global__ void k_zero(int* __restrict__ p, int n) {
    int i = blockIdx.x * blockDim.x + threadIdx.x;
    if (i < n) p[i] = 0;
}

// ---------------- bucket histogram (LDS-aggregated) ----------------
__global__ __launch_bounds__(256) void k_bhist(const int* __restrict__ dst, int E,
                                               int nbuck, int* __restrict__ bucket_total) {
    __shared__ int hist[MAXBUCK];
    int t = threadIdx.x;
    for (int i = t; i < MAXBUCK; i += 256) hist[i] = 0;
    __syncthreads();
    for (int e = blockIdx.x * 256 + t; e < E; e += gridDim.x * 256)
        atomicAdd(&hist[dst[e] >> 8], 1);
    __syncthreads();
    for (int i = t; i < nbuck; i += 256)
        if (hist[i]) atomicAdd(&bucket_total[i], hist[i]);
}

// ---------------- scan bucket totals (one block) ----------------
__global__ __launch_bounds__(512) void k_bscan(const int* __restrict__ bucket_total,
                                               int* __restrict__ bucket_base,
                                               int* __restrict__ bucket_cursor, int nbuck) {
    __shared__ int sh[512];
    int t = threadIdx.x;
    int v = (t < nbuck) ? bucket_total[t] : 0;
    sh[t] = v; __syncthreads();
    for (int off = 1; off < 512; off <<= 1) {
        int tmp = (t >= off) ? sh[t - off] : 0; __syncthreads();
        sh[t] += tmp; __syncthreads();
    }
    int ex = sh[t] - v;  // exclusive
    if (t < nbuck) { bucket_base[t] = ex; bucket_cursor[t] = ex; }
    if (t == 511) bucket_base[nbuck] = sh[511];  // total = E
}

// ---------------- bin edges into bucket regions ----------------
// 4096 edges per block; per-block contiguous reservation per bucket keeps
// the 8B pair-writes line-dense despite being "scattered".
__global__ __launch_bounds__(256) void k_bin(const int* __restrict__ src,
                                             const int* __restrict__ dst, int E,
                                             int nbuck, int* __restrict__ bucket_cursor,
                                             int2* __restrict__ pairs) {
    __shared__ int hist[MAXBUCK];
    __shared__ int base_l[MAXBUCK];
    __shared__ int cur[MAXBUCK];
    int t = threadIdx.x;
    int e0 = blockIdx.x * 4096;
    for (int i = t; i < MAXBUCK; i += 256) { hist[i] = 0; cur[i] = 0; }
    __syncthreads();
    for (int i = t; i < 4096; i += 256) {
        int e = e0 + i;
        if (e < E) atomicAdd(&hist[dst[e] >> 8], 1);
    }
    __syncthreads();
    for (int i = t; i < nbuck; i += 256)
        base_l[i] = hist[i] ? atomicAdd(&bucket_cursor[i], hist[i]) : 0;
    __syncthreads();
    for (int i = t; i < 4096; i += 256) {
        int e = e0 + i;
        if (e < E) {
            int d = dst[e];
            int b = d >> 8;
            int p = atomicAdd(&cur[b], 1);
            pairs[base_l[b] + p] = make_int2(src[e], d);
        }
    }
}

// ---------------- per-bucket CSR fill + cnt/rowstart/dinv ----------------
// one block per bucket; all cursors/counts/scans in LDS; srclist writes land in
// the bucket's ~16KB contiguous CSR window.
__global__ __launch_bounds__(256) void k_fill2(const int2* __restrict__ pairs,
                                               const int* __restrict__ bucket_base,
                                               int N, int* __restrict__ srclist,
                                               int* __restrict__ rowstart,
                                               int* __restrict__ cnt,
                                               float* __restrict__ dinv) {
    __shared__ int hist[256];
    __shared__ int sh[256];
    __shared__ int rs_ex[256];
    __shared__ int cur[256];
    int b = blockIdx.x;
    int t = threadIdx.x;
    int start = bucket_base[b], end = bucket_base[b + 1];
    int node0 = b << 8;

    hist[t] = 0;
    __syncthreads();
    for (int e = start + t; e < end; e += 256)
        atomicAdd(&hist[pairs[e].y & 255], 1);
    __syncthreads();
    // exclusive scan of hist
    int v = hist[t];
    sh[t] = v; __syncthreads();
    for (int off = 1; off < 256; off <<= 1) {
        int tmp = (t >= off) ? sh[t - off] : 0; __syncthreads();
        sh[t] += tmp; __syncthreads();
    }
    rs_ex[t] = sh[t] - v;
    cur[t] = 0;
    int node = node0 + t;
    if (node < N) {
        rowstart[node] = start + rs_ex[t];
        cnt[node] = v;
        dinv[node] = rsqrtf((float)(v + 1));
    }
    __syncthreads();
    for (int e = start + t; e < end; e += 256) {
        int2 pr = pairs[e];
        int dl = pr.y & 255;
        int p = atomicAdd(&cur[dl], 1);
        srclist[start + rs_ex[dl] + p] = pr.x;
    }
}

// ---------------- layer 1 GEMM: h1s = (x @ W1) * dinv ----------------
__global__ __launch_bounds__(256) void k_gemm1(const float* __restrict__ x,
                                               const float* __restrict__ W1,
                                               const float* __restrict__ dinv,
                                               float* __restrict__ h1s, int n) {
    __shared__ float W1s[128 * 64];  // 32 KB
    __shared__ float xs[4][128];
    int t = threadIdx.x;
    for (int i = t; i < 128 * 64; i += 256) W1s[i] = W1[i];
    int node0 = blockIdx.x * 4;
    for (int i = t; i < 4 * 128; i += 256) {
        int nl = i >> 7, k = i & 127;
        int node = node0 + nl;
        xs[nl][k] = (node < n) ? x[(size_t)node * 128 + k] : 0.0f;
    }
    __syncthreads();
    int nl = t >> 6, c = t & 63;
    int node = node0 + nl;
    if (node < n) {
        float acc = 0.0f;
#pragma unroll 8
        for (int k = 0; k < 128; k++) acc = fmaf(xs[nl][k], W1s[k * 64 + c], acc);
        h1s[(size_t)node * 64 + c] = acc * dinv[node];
    }
}

// ------- L1 gather + finalize + GEMM2: h2s = (relu((gather+self)*dinv + b1) @ W2) * dinv ----
__global__ __launch_bounds__(256) void k_gather_l1(const int* __restrict__ rowstart,
                                                   const int* __restrict__ cnt,
                                                   const int* __restrict__ srclist,
                                                   const float* __restrict__ h1s,
                                                   const float* __restrict__ dinv,
                                                   const float* __restrict__ b1,
                                                   const float* __restrict__ W2,
                                                   float* __restrict__ h2s, int n) {
    __shared__ float W2s[64 * 32];  // 8 KB
    __shared__ float hb[4][64];
    int t = threadIdx.x;
    for (int i = t; i < 64 * 32; i += 256) W2s[i] = W2[i];
    int wid = t >> 6, lane = t & 63;
    int node = blockIdx.x * 4 + wid;
    bool valid = (node < n);

    int row = valid ? rowstart[node] : 0;
    int m_all = valid ? cnt[node] : 0;
    float acc = 0.0f;
    for (int j0 = 0; j0 < m_all; j0 += 64) {
        int m = min(64, m_all - j0);  // wave-uniform
        int sidx = (lane < m) ? srclist[row + j0 + lane] : 0;
        int j = 0;
        for (; j + 4 <= m; j += 4) {
            int s0 = __shfl(sidx, j), s1 = __shfl(sidx, j + 1);
            int s2 = __shfl(sidx, j + 2), s3 = __shfl(sidx, j + 3);
            float a0 = h1s[(size_t)s0 * 64 + lane];
            float a1 = h1s[(size_t)s1 * 64 + lane];
            float a2 = h1s[(size_t)s2 * 64 + lane];
            float a3 = h1s[(size_t)s3 * 64 + lane];
            acc += (a0 + a1) + (a2 + a3);
        }
        for (; j < m; j++) {
            int s = __shfl(sidx, j);
            acc += h1s[(size_t)s * 64 + lane];
        }
    }
    float di = valid ? dinv[node] : 0.0f;
    if (valid) {
        float v = (acc + h1s[(size_t)node * 64 + lane]) * di + b1[lane];  // self-loop folded
        hb[wid][lane] = fmaxf(v, 0.0f);
    }
    __syncthreads();  // covers both W2s staging and hb writes
    if (valid && lane < 32) {
        float s = 0.0f;
#pragma unroll 8
        for (int k = 0; k < 64; k++) s = fmaf(hb[wid][k], W2s[k * 32 + lane], s);
        h2s[(size_t)node * 32 + lane] = s * di;
    }
}

// ------- L2 gather + finalize: out = (gather+self)*dinv + b2 ----
__global__ __launch_bounds__(256) void k_gather_l2(const int* __restrict__ rowstart,
                                                   const int* __restrict__ cnt,
                                                   const int* __restrict__ srclist,
                                                   const float* __restrict__ h2s,
                                                   const float* __restrict__ dinv,
                                                   const float* __restrict__ b2v,
                                                   float* __restrict__ out, int n) {
    int t = threadIdx.x;
    int wid = t >> 6, lane = t & 63;
    int node = blockIdx.x * 4 + wid;
    if (node >= n) return;  // whole wave exits together; no barriers below
    int c = lane & 31, half = lane >> 5;

    int row = rowstart[node], m_all = cnt[node];
    float acc = 0.0f;
    for (int j0 = 0; j0 < m_all; j0 += 64) {
        int m = min(64, m_all - j0);  // wave-uniform, >= 1
        int sidx = (lane < m) ? srclist[row + j0 + lane] : 0;
        int jj = 0;
        for (; jj + 8 <= m; jj += 8) {
            int s0 = __shfl(sidx, jj + half),     s1 = __shfl(sidx, jj + 2 + half);
            int s2 = __shfl(sidx, jj + 4 + half), s3 = __shfl(sidx, jj + 6 + half);
            float a0 = h2s[(size_t)s0 * 32 + c];
            float a1 = h2s[(size_t)s1 * 32 + c];
            float a2 = h2s[(size_t)s2 * 32 + c];
            float a3 = h2s[(size_t)s3 * 32 + c];
            acc += (a0 + a1) + (a2 + a3);
        }
        for (; jj < m; jj += 2) {
            int jidx = jj + half;
            int s = __shfl(sidx, min(jidx, m - 1));  // uniform shfl; clamp lane
            if (jidx < m) acc += h2s[(size_t)s * 32 + c];  // predicate the use only
        }
    }
    acc += __shfl_xor(acc, 32);  // combine halves (all lanes active)
    if (half == 0) {
        float di = dinv[node];
        out[(size_t)node * 32 + c] = (acc + h2s[(size_t)node * 32 + c]) * di + b2v[c];
    }
}

extern "C" void kernel_launch(void* const* d_in, const int* in_sizes, int n_in,
                              void* d_out, int out_size, void* d_ws, size_t ws_size,
                              hipStream_t stream) {
    const float* x  = (const float*)d_in[0];
    const int*   ei = (const int*)d_in[1];
    const float* W1 = (const float*)d_in[2];
    const float* b1 = (const float*)d_in[3];
    const float* W2 = (const float*)d_in[4];
    const float* b2 = (const float*)d_in[5];
    float* out = (float*)d_out;

    const int N = in_sizes[0] / 128;  // 100000
    const int E = in_sizes[1] / 2;    // 1600000
    const int* src = ei;
    const int* dst = ei + E;
    const int nbuck = (N + 255) >> 8;  // 391 (<= MAXBUCK)

    char* p = (char*)d_ws;
    int2* pairs        = (int2*)p;      p += (size_t)E * 8;       // 12.8 MB (8B aligned first)
    int* srclist       = (int*)p;       p += (size_t)E * 4;       // 6.4 MB
    int* bucket_total  = (int*)p;       p += MAXBUCK * 4;
    int* bucket_base   = (int*)p;       p += (MAXBUCK + 1) * 4;
    int* bucket_cursor = (int*)p;       p += MAXBUCK * 4;
    int* rowstart      = (int*)p;       p += (size_t)N * 4;
    int* cnt           = (int*)p;       p += (size_t)N * 4;
    float* dinv        = (float*)p;     p += (size_t)N * 4;
    float* h1s         = (float*)p;     p += (size_t)N * 64 * 4;  // 25.6 MB
    float* h2s         = (float*)p;     p += (size_t)N * 32 * 4;  // 12.8 MB

    k_zero<<<(MAXBUCK + 255) / 256, 256, 0, stream>>>(bucket_total, MAXBUCK);
    k_bhist<<<512, 256, 0, stream>>>(dst, E, nbuck, bucket_total);
    k_bscan<<<1, 512, 0, stream>>>(bucket_total, bucket_base, bucket_cursor, nbuck);
    k_bin<<<(E + 4095) / 4096, 256, 0, stream>>>(src, dst, E, nbuck, bucket_cursor, pairs);
    k_fill2<<<nbuck, 256, 0, stream>>>(pairs, bucket_base, N, srclist, rowstart, cnt, dinv);

    k_gemm1<<<(N + 3) / 4, 256, 0, stream>>>(x, W1, dinv, h1s, N);
    k_gather_l1<<<(N + 3) / 4, 256, 0, stream>>>(rowstart, cnt, srclist, h1s, dinv, b1, W2, h2s, N);
    k_gather_l2<<<(N + 3) / 4, 256, 0, stream>>>(rowstart, cnt, srclist, h2s, dinv, b2, out, N);
}